// Round 1
// baseline (571.203 us; speedup 1.0000x reference)
//
#include <hip/hip_runtime.h>
#include <math.h>

#define N_NODES 8192
#define D_FEAT  512
#define H_HEADS 8
#define DKH     64
#define DEG     16
#define E_EDGES (N_NODES * DEG)
#define FEAT_W  (H_HEADS * (DKH + 4))   // 544
#define OUT_W   512

// ---------------------------------------------------------------------------
// Generic fp32 GEMM: C[M,N] = alpha * A[M,K] @ B[N,K]^T + (bias ? bias[col] : 0)
// A row-major [M,K], B row-major [N,K] (i.e. C = A·B^T), C row-major [M,N].
// Requires M % 64 == 0 and K % 16 == 0 (true for all call sites here);
// N is bounds-checked (needed for the 24-wide qv projection).
// ---------------------------------------------------------------------------
#define BM 64
#define BN 64
#define BK 16

__global__ __launch_bounds__(256) void gemm_abT(
    const float* __restrict__ A, const float* __restrict__ B,
    const float* __restrict__ bias, float* __restrict__ C,
    int M, int N, int K, float alpha)
{
    __shared__ float As[BK][BM + 1];
    __shared__ float Bs[BK][BN + 1];

    const int bm = blockIdx.y * BM;
    const int bn = blockIdx.x * BN;
    const int tid = threadIdx.x;
    const int tx = tid & 15;
    const int ty = tid >> 4;

    float acc[4][4] = {};

    for (int k0 = 0; k0 < K; k0 += BK) {
        // Load A tile: 64 rows x 16 k, one float4 per thread along K.
        {
            const int row = tid >> 2;          // 0..63
            const int c4  = tid & 3;           // 0..3
            const float4 a = *(const float4*)(A + (size_t)(bm + row) * K + k0 + c4 * 4);
            As[c4 * 4 + 0][row] = a.x;
            As[c4 * 4 + 1][row] = a.y;
            As[c4 * 4 + 2][row] = a.z;
            As[c4 * 4 + 3][row] = a.w;
        }
        // Load B tile (guard N).
        {
            const int row = tid >> 2;
            const int c4  = tid & 3;
            float4 b = make_float4(0.f, 0.f, 0.f, 0.f);
            if (bn + row < N)
                b = *(const float4*)(B + (size_t)(bn + row) * K + k0 + c4 * 4);
            Bs[c4 * 4 + 0][row] = b.x;
            Bs[c4 * 4 + 1][row] = b.y;
            Bs[c4 * 4 + 2][row] = b.z;
            Bs[c4 * 4 + 3][row] = b.w;
        }
        __syncthreads();

        #pragma unroll
        for (int kk = 0; kk < BK; ++kk) {
            float a_r[4], b_r[4];
            #pragma unroll
            for (int i = 0; i < 4; ++i) a_r[i] = As[kk][ty + 16 * i];
            #pragma unroll
            for (int j = 0; j < 4; ++j) b_r[j] = Bs[kk][tx + 16 * j];
            #pragma unroll
            for (int i = 0; i < 4; ++i)
                #pragma unroll
                for (int j = 0; j < 4; ++j)
                    acc[i][j] += a_r[i] * b_r[j];
        }
        __syncthreads();
    }

    #pragma unroll
    for (int i = 0; i < 4; ++i) {
        const int row = bm + ty + 16 * i;
        #pragma unroll
        for (int j = 0; j < 4; ++j) {
            const int col = bn + tx + 16 * j;
            if (col < N) {
                float v = alpha * acc[i][j];
                if (bias) v += bias[col];
                C[(size_t)row * N + col] = v;
            }
        }
    }
}

// ---------------------------------------------------------------------------
// Edge stage: one thread per (node, head). row_index == repeat(arange(N), DEG)
// by construction, so edges of node n are [n*DEG, n*DEG+DEG) and the segment
// softmax is a dense 16-way softmax in registers.
// ---------------------------------------------------------------------------
__global__ __launch_bounds__(256) void edge_kernel(
    const float* __restrict__ q_all,    // [N, H*DK] pre-scaled by 1/sqrt(DK)
    const float* __restrict__ k_all,    // [N, H*DK] (projection of x, pre-gather)
    const float* __restrict__ v_all,    // [N, H*DK]
    const float* __restrict__ qv_all,   // [N, H*3]
    const int*   __restrict__ col_index,  // [E]
    const int*   __restrict__ to_col,     // [M]
    const float* __restrict__ att_bias,   // [H, E]
    const float* __restrict__ dist,       // [E]
    const float* __restrict__ pos,        // [N, 3]
    const float* __restrict__ col_pos,    // [M, 3]
    float* __restrict__ feat)             // [N, 544]
{
    const int t = blockIdx.x * blockDim.x + threadIdx.x;
    const int h = t & (H_HEADS - 1);
    const int n = t >> 3;
    if (n >= N_NODES) return;

    // q fragment: 64 floats = 16 float4
    const float4* qp = (const float4*)(q_all + (size_t)n * (H_HEADS * DKH) + h * DKH);
    float4 q[16];
    #pragma unroll
    for (int i = 0; i < 16; ++i) q[i] = qp[i];

    const float qv0 = qv_all[n * (H_HEADS * 3) + h * 3 + 0];
    const float qv1 = qv_all[n * (H_HEADS * 3) + h * 3 + 1];
    const float qv2 = qv_all[n * (H_HEADS * 3) + h * 3 + 2];
    const float px = pos[3 * n + 0], py = pos[3 * n + 1], pz = pos[3 * n + 2];

    float logit[DEG];

    #pragma unroll
    for (int j = 0; j < DEG; ++j) {
        const int e  = n * DEG + j;
        const int c  = col_index[e];
        const int cc = to_col[c];
        const float4* kp = (const float4*)(k_all + (size_t)cc * (H_HEADS * DKH) + h * DKH);
        float dot = 0.f;
        #pragma unroll
        for (int i = 0; i < 16; ++i) {
            const float4 kv = kp[i];
            dot += q[i].x * kv.x + q[i].y * kv.y + q[i].z * kv.z + q[i].w * kv.w;
        }
        const float rx = col_pos[3 * c + 0] - px;
        const float ry = col_pos[3 * c + 1] - py;
        const float rz = col_pos[3 * c + 2] - pz;
        const float ang = qv0 * rx + qv1 * ry + qv2 * rz;
        const float d = dist[e];
        const float invd = (d == 0.f) ? 0.f : (1.f / d);   // dist==0 -> masked to inf
        logit[j] = dot + att_bias[(size_t)h * E_EDGES + e] + ang * invd;
    }

    // softmax over the 16 edges
    float m = logit[0];
    #pragma unroll
    for (int j = 1; j < DEG; ++j) m = fmaxf(m, logit[j]);
    float s = 0.f;
    #pragma unroll
    for (int j = 0; j < DEG; ++j) {
        logit[j] = expf(logit[j] - m);
        s += logit[j];
    }
    const float inv_s = 1.f / s;

    // pass B: accumulate y (64), dst_vec (3), avg_inv_dist (1)
    float4 y[16];
    #pragma unroll
    for (int i = 0; i < 16; ++i) y[i] = make_float4(0.f, 0.f, 0.f, 0.f);
    float dx = 0.f, dy = 0.f, dz = 0.f, aid = 0.f;

    #pragma unroll
    for (int j = 0; j < DEG; ++j) {
        const int e  = n * DEG + j;
        const int c  = col_index[e];
        const int cc = to_col[c];
        const float a = logit[j] * inv_s;
        const float d = dist[e];
        const float invd = (d == 0.f) ? 0.f : (1.f / d);
        const float na = a * invd;
        const float4* vp = (const float4*)(v_all + (size_t)cc * (H_HEADS * DKH) + h * DKH);
        #pragma unroll
        for (int i = 0; i < 16; ++i) {
            const float4 vv = vp[i];
            y[i].x += a * vv.x; y[i].y += a * vv.y;
            y[i].z += a * vv.z; y[i].w += a * vv.w;
        }
        dx += na * col_pos[3 * c + 0];
        dy += na * col_pos[3 * c + 1];
        dz += na * col_pos[3 * c + 2];
        aid += na;
    }

    dx -= aid * px; dy -= aid * py; dz -= aid * pz;
    const float nrm = sqrtf(dx * dx + dy * dy + dz * dz);
    const float rn = 1.f / fmaxf(nrm, 1e-12f);

    float* f = feat + (size_t)n * FEAT_W + h * (DKH + 4);
    #pragma unroll
    for (int i = 0; i < 16; ++i) ((float4*)f)[i] = y[i];
    f[64] = dx * rn;
    f[65] = dy * rn;
    f[66] = dz * rn;
    f[67] = aid;
}

// ---------------------------------------------------------------------------
extern "C" void kernel_launch(void* const* d_in, const int* in_sizes, int n_in,
                              void* d_out, int out_size, void* d_ws, size_t ws_size,
                              hipStream_t stream)
{
    const float* x         = (const float*)d_in[0];   // [N, D]
    // d_in[1] = row_index (implicit: repeat(arange(N), DEG)) — unused
    const int*   col_index = (const int*)d_in[2];     // [E]
    const int*   to_col    = (const int*)d_in[3];     // [M]
    const float* att_bias  = (const float*)d_in[4];   // [H, E]
    const float* dist      = (const float*)d_in[5];   // [E]
    const float* pos       = (const float*)d_in[6];   // [N, 3]
    const float* col_pos   = (const float*)d_in[7];   // [M, 3]
    const float* Wq        = (const float*)d_in[8];   // [H*DK, D] flat
    const float* Wqv       = (const float*)d_in[9];   // [H*3, D] flat
    const float* Wk        = (const float*)d_in[10];  // [H*DK, D]
    const float* Wv        = (const float*)d_in[11];  // [H*DK, D]
    const float* Wout      = (const float*)d_in[12];  // [512, 544]
    const float* bout      = (const float*)d_in[13];  // [512]
    float* out = (float*)d_out;

    float* ws     = (float*)d_ws;
    float* q_all  = ws;                                   // N*512
    float* k_all  = q_all + (size_t)N_NODES * 512;        // N*512
    float* v_all  = k_all + (size_t)N_NODES * 512;        // N*512
    float* qv_all = v_all + (size_t)N_NODES * 512;        // N*24
    float* feat   = qv_all + (size_t)N_NODES * 24;        // N*544

    const float scale = 1.0f / sqrtf((float)DKH);

    // Projections
    dim3 blk(256);
    dim3 grd_qkv((512 + BN - 1) / BN, N_NODES / BM);
    hipLaunchKernelGGL(gemm_abT, grd_qkv, blk, 0, stream,
                       x, Wq, (const float*)nullptr, q_all, N_NODES, 512, D_FEAT, scale);
    hipLaunchKernelGGL(gemm_abT, grd_qkv, blk, 0, stream,
                       x, Wk, (const float*)nullptr, k_all, N_NODES, 512, D_FEAT, 1.0f);
    hipLaunchKernelGGL(gemm_abT, grd_qkv, blk, 0, stream,
                       x, Wv, (const float*)nullptr, v_all, N_NODES, 512, D_FEAT, 1.0f);
    dim3 grd_qv((24 + BN - 1) / BN, N_NODES / BM);
    hipLaunchKernelGGL(gemm_abT, grd_qv, blk, 0, stream,
                       x, Wqv, (const float*)nullptr, qv_all, N_NODES, 24, D_FEAT, 1.0f);

    // Edge stage -> feat [N, 544]
    dim3 grd_edge((N_NODES * H_HEADS + 255) / 256);
    hipLaunchKernelGGL(edge_kernel, grd_edge, blk, 0, stream,
                       q_all, k_all, v_all, qv_all, col_index, to_col,
                       att_bias, dist, pos, col_pos, feat);

    // Output GEMM: out = feat @ Wout^T + bout
    dim3 grd_out((OUT_W + BN - 1) / BN, N_NODES / BM);
    hipLaunchKernelGGL(gemm_abT, grd_out, blk, 0, stream,
                       feat, Wout, bout, out, N_NODES, OUT_W, FEAT_W, 1.0f);
}

// Round 2
// 307.048 us; speedup vs baseline: 1.8603x; 1.8603x over previous
//
#include <hip/hip_runtime.h>
#include <math.h>

#define N_NODES 8192
#define D_FEAT  512
#define H_HEADS 8
#define DKH     64
#define DEG     16
#define E_EDGES (N_NODES * DEG)
#define FEAT_W  (H_HEADS * (DKH + 4))   // 544
#define OUT_W   512

typedef unsigned short u16;
typedef __attribute__((ext_vector_type(8))) short short8;   // 8 bf16 (4 VGPRs)
typedef __attribute__((ext_vector_type(4))) float f32x4;    // 4 fp32 acc

// ---- bf16 helpers (RNE) ----------------------------------------------------
__device__ __forceinline__ u16 f2bf(float f) {
    union { float f; unsigned u; } c; c.f = f;
    unsigned u = c.u;
    unsigned r = u + 0x7FFFu + ((u >> 16) & 1u);
    return (u16)(r >> 16);
}
__device__ __forceinline__ float bf2f(u16 h) {
    union { unsigned u; float f; } c; c.u = ((unsigned)h) << 16;
    return c.f;
}

// ---- async global->LDS 16B -------------------------------------------------
__device__ __forceinline__ void async16(const void* g, void* l) {
#if __has_builtin(__builtin_amdgcn_global_load_lds)
    __builtin_amdgcn_global_load_lds(
        (const __attribute__((address_space(1))) void*)g,
        (__attribute__((address_space(3))) void*)l, 16, 0, 0);
#else
    *(float4*)l = *(const float4*)g;
#endif
}

// ---------------------------------------------------------------------------
// Split-bf16 MFMA GEMM: C[M,N] = (Ah+Al)[M,K] * (Bh+Bl)[N,K]^T + bias
// 3-pass: Ah*Bh + Ah*Bl + Al*Bh  (~fp32 precision). HAS_AL=false -> 2-pass
// (A is exactly bf16). Requires M%128==0, N%128==0, K%32==0.
// Block: 256 threads = 4 waves; 128x128 tile; wave = 64x64 = 4x4 MFMA tiles.
// ---------------------------------------------------------------------------
template<bool HAS_AL, bool BF16_OUT>
__global__ __launch_bounds__(256) void gemm_split(
    const u16* __restrict__ Ah, const u16* __restrict__ Al,
    const u16* __restrict__ Bh, const u16* __restrict__ Bl,
    const float* __restrict__ bias, void* __restrict__ Cout,
    int M, int N, int K)
{
    __shared__ u16 sAh[128 * 32];
    __shared__ u16 sAl[128 * 32];
    __shared__ u16 sBh[128 * 32];
    __shared__ u16 sBl[128 * 32];

    const int tid  = threadIdx.x;
    const int bm   = blockIdx.y * 128;
    const int bn   = blockIdx.x * 128;
    const int wave = tid >> 6;
    const int lane = tid & 63;
    const int wr   = (wave >> 1) * 64;   // wave row offset in tile
    const int wc   = (wave & 1) * 64;    // wave col offset in tile
    const int lrow = lane & 15;
    const int quad = lane >> 4;

    f32x4 acc[4][4];
    #pragma unroll
    for (int i = 0; i < 4; ++i)
        #pragma unroll
        for (int j = 0; j < 4; ++j) {
            f32x4 z = {0.f, 0.f, 0.f, 0.f};
            acc[i][j] = z;
        }

    for (int k0 = 0; k0 < K; k0 += 32) {
        // Stage 128x32 bf16 tiles (8 KB each): 512 chunks of 16B, 2 per thread.
        #pragma unroll
        for (int i = 0; i < 2; ++i) {
            const int lin = i * 256 + tid;       // 16B-chunk index
            const int row = lin >> 2;            // 0..127
            const int seg = (lin & 3) << 3;      // k element offset 0/8/16/24
            const int loff = lin << 3;           // ushort offset in LDS
            const size_t ga = (size_t)(bm + row) * K + k0 + seg;
            const size_t gb = (size_t)(bn + row) * K + k0 + seg;
            async16(Ah + ga, sAh + loff);
            if (HAS_AL) async16(Al + ga, sAl + loff);
            async16(Bh + gb, sBh + loff);
            async16(Bl + gb, sBl + loff);
        }
        __syncthreads();

        short8 a_h[4], a_l[4], b_h[4], b_l[4];
        #pragma unroll
        for (int t = 0; t < 4; ++t) {
            const int ar = (wr + t * 16 + lrow) * 32 + quad * 8;
            const int br = (wc + t * 16 + lrow) * 32 + quad * 8;
            a_h[t] = *(const short8*)&sAh[ar];
            if (HAS_AL) a_l[t] = *(const short8*)&sAl[ar];
            b_h[t] = *(const short8*)&sBh[br];
            b_l[t] = *(const short8*)&sBl[br];
        }

        #pragma unroll
        for (int mt = 0; mt < 4; ++mt)
            #pragma unroll
            for (int nt = 0; nt < 4; ++nt) {
                acc[mt][nt] = __builtin_amdgcn_mfma_f32_16x16x32_bf16(
                    a_h[mt], b_h[nt], acc[mt][nt], 0, 0, 0);
                acc[mt][nt] = __builtin_amdgcn_mfma_f32_16x16x32_bf16(
                    a_h[mt], b_l[nt], acc[mt][nt], 0, 0, 0);
                if (HAS_AL)
                    acc[mt][nt] = __builtin_amdgcn_mfma_f32_16x16x32_bf16(
                        a_l[mt], b_h[nt], acc[mt][nt], 0, 0, 0);
            }
        __syncthreads();
    }

    // Epilogue: C/D layout col=lane&15, row=quad*4+r
    #pragma unroll
    for (int nt = 0; nt < 4; ++nt) {
        const int col = bn + wc + nt * 16 + lrow;
        const float bb = bias ? bias[col] : 0.f;
        #pragma unroll
        for (int mt = 0; mt < 4; ++mt) {
            #pragma unroll
            for (int r = 0; r < 4; ++r) {
                const int row = bm + wr + mt * 16 + quad * 4 + r;
                const float v = acc[mt][nt][r] + bb;
                if (BF16_OUT)
                    ((u16*)Cout)[(size_t)row * N + col] = f2bf(v);
                else
                    ((float*)Cout)[(size_t)row * N + col] = v;
            }
        }
    }
}

// ---------------------------------------------------------------------------
// fp32 -> (hi bf16, lo bf16) split, float4-vectorized, optional scale.
// ---------------------------------------------------------------------------
__global__ __launch_bounds__(256) void split2(
    const float* __restrict__ in, u16* __restrict__ hi, u16* __restrict__ lo,
    int n4, float scale)
{
    const int i = blockIdx.x * 256 + threadIdx.x;
    if (i >= n4) return;
    float4 v = ((const float4*)in)[i];
    v.x *= scale; v.y *= scale; v.z *= scale; v.w *= scale;
    ushort4 h, l;
    h.x = f2bf(v.x); l.x = f2bf(v.x - bf2f(h.x));
    h.y = f2bf(v.y); l.y = f2bf(v.y - bf2f(h.y));
    h.z = f2bf(v.z); l.z = f2bf(v.z - bf2f(h.z));
    h.w = f2bf(v.w); l.w = f2bf(v.w - bf2f(h.w));
    ((ushort4*)hi)[i] = h;
    ((ushort4*)lo)[i] = l;
}

// ---------------------------------------------------------------------------
// Legacy fp32 tiled GEMM (used only for the tiny 24-wide qv projection).
// C[M,N] = alpha * A[M,K] @ B[N,K]^T ; N bounds-checked.
// ---------------------------------------------------------------------------
#define BM 64
#define BN 64
#define BK 16
__global__ __launch_bounds__(256) void gemm_abT(
    const float* __restrict__ A, const float* __restrict__ B,
    const float* __restrict__ bias, float* __restrict__ C,
    int M, int N, int K, float alpha)
{
    __shared__ float As[BK][BM + 1];
    __shared__ float Bs[BK][BN + 1];
    const int bm = blockIdx.y * BM;
    const int bn = blockIdx.x * BN;
    const int tid = threadIdx.x;
    const int tx = tid & 15;
    const int ty = tid >> 4;
    float acc[4][4] = {};
    for (int k0 = 0; k0 < K; k0 += BK) {
        {
            const int row = tid >> 2, c4 = tid & 3;
            const float4 a = *(const float4*)(A + (size_t)(bm + row) * K + k0 + c4 * 4);
            As[c4 * 4 + 0][row] = a.x; As[c4 * 4 + 1][row] = a.y;
            As[c4 * 4 + 2][row] = a.z; As[c4 * 4 + 3][row] = a.w;
        }
        {
            const int row = tid >> 2, c4 = tid & 3;
            float4 b = make_float4(0.f, 0.f, 0.f, 0.f);
            if (bn + row < N)
                b = *(const float4*)(B + (size_t)(bn + row) * K + k0 + c4 * 4);
            Bs[c4 * 4 + 0][row] = b.x; Bs[c4 * 4 + 1][row] = b.y;
            Bs[c4 * 4 + 2][row] = b.z; Bs[c4 * 4 + 3][row] = b.w;
        }
        __syncthreads();
        #pragma unroll
        for (int kk = 0; kk < BK; ++kk) {
            float a_r[4], b_r[4];
            #pragma unroll
            for (int i = 0; i < 4; ++i) a_r[i] = As[kk][ty + 16 * i];
            #pragma unroll
            for (int j = 0; j < 4; ++j) b_r[j] = Bs[kk][tx + 16 * j];
            #pragma unroll
            for (int i = 0; i < 4; ++i)
                #pragma unroll
                for (int j = 0; j < 4; ++j)
                    acc[i][j] += a_r[i] * b_r[j];
        }
        __syncthreads();
    }
    #pragma unroll
    for (int i = 0; i < 4; ++i) {
        const int row = bm + ty + 16 * i;
        #pragma unroll
        for (int j = 0; j < 4; ++j) {
            const int col = bn + tx + 16 * j;
            if (col < N) {
                float v = alpha * acc[i][j];
                if (bias) v += bias[col];
                C[(size_t)row * N + col] = v;
            }
        }
    }
}

// ---------------------------------------------------------------------------
// Edge stage: 16 lanes per (node, head); lane owns 4 of the 64 dk dims.
// row_index == repeat(arange(N), DEG): dense 16-way softmax per (n,h).
// q,k read fp32 from qk[8192,1024] (q cols 0..511, k cols 512..1023);
// v read bf16 from v_bf[8192,512]. Writes feat bf16 [8192,544].
// ---------------------------------------------------------------------------
__global__ __launch_bounds__(256) void edge_kernel(
    const float* __restrict__ qk, const u16* __restrict__ v_bf,
    const float* __restrict__ qv_all,
    const int* __restrict__ col_index, const int* __restrict__ to_col,
    const float* __restrict__ att_bias, const float* __restrict__ dist,
    const float* __restrict__ pos, const float* __restrict__ col_pos,
    u16* __restrict__ feat)
{
    const int tid  = threadIdx.x;
    const int lane = tid & 15;
    const int nh   = blockIdx.x * 16 + (tid >> 4);
    const int n = nh >> 3;
    const int h = nh & 7;

    const float4 q = *(const float4*)(qk + (size_t)n * 1024 + h * DKH + lane * 4);
    const float qv0 = qv_all[n * 24 + h * 3 + 0];
    const float qv1 = qv_all[n * 24 + h * 3 + 1];
    const float qv2 = qv_all[n * 24 + h * 3 + 2];
    const float px = pos[3 * n + 0], py = pos[3 * n + 1], pz = pos[3 * n + 2];

    float logit[DEG], invds[DEG];
    int cs[DEG], ccs[DEG];

    #pragma unroll
    for (int j = 0; j < DEG; ++j) {
        const int e  = n * DEG + j;
        const int c  = col_index[e];
        const int cc = to_col[c];
        cs[j] = c; ccs[j] = cc;
        const float4 kf = *(const float4*)(qk + (size_t)cc * 1024 + 512 + h * DKH + lane * 4);
        float dot = q.x * kf.x + q.y * kf.y + q.z * kf.z + q.w * kf.w;
        #pragma unroll
        for (int off = 1; off < 16; off <<= 1) dot += __shfl_xor(dot, off, 16);
        const float rx = col_pos[3 * c + 0] - px;
        const float ry = col_pos[3 * c + 1] - py;
        const float rz = col_pos[3 * c + 2] - pz;
        const float ang = qv0 * rx + qv1 * ry + qv2 * rz;
        const float d = dist[e];
        const float invd = (d == 0.f) ? 0.f : (1.f / d);
        invds[j] = invd;
        logit[j] = dot + att_bias[(size_t)h * E_EDGES + e] + ang * invd;
    }

    float m = logit[0];
    #pragma unroll
    for (int j = 1; j < DEG; ++j) m = fmaxf(m, logit[j]);
    float s = 0.f;
    #pragma unroll
    for (int j = 0; j < DEG; ++j) { logit[j] = __expf(logit[j] - m); s += logit[j]; }
    const float inv_s = 1.f / s;

    float4 y = make_float4(0.f, 0.f, 0.f, 0.f);
    float dx = 0.f, dy = 0.f, dz = 0.f, aid = 0.f;
    #pragma unroll
    for (int j = 0; j < DEG; ++j) {
        const float a  = logit[j] * inv_s;
        const float na = a * invds[j];
        const ushort4 vv = *(const ushort4*)(v_bf + (size_t)ccs[j] * 512 + h * DKH + lane * 4);
        y.x += a * bf2f(vv.x); y.y += a * bf2f(vv.y);
        y.z += a * bf2f(vv.z); y.w += a * bf2f(vv.w);
        const int c = cs[j];
        dx += na * col_pos[3 * c + 0];
        dy += na * col_pos[3 * c + 1];
        dz += na * col_pos[3 * c + 2];
        aid += na;
    }
    dx -= aid * px; dy -= aid * py; dz -= aid * pz;

    u16* f = feat + (size_t)n * FEAT_W + h * (DKH + 4);
    ushort4 yo;
    yo.x = f2bf(y.x); yo.y = f2bf(y.y); yo.z = f2bf(y.z); yo.w = f2bf(y.w);
    *(ushort4*)(f + lane * 4) = yo;
    if (lane == 0) {
        const float nrm = sqrtf(dx * dx + dy * dy + dz * dz);
        const float rn = 1.f / fmaxf(nrm, 1e-12f);
        ushort4 ex;
        ex.x = f2bf(dx * rn); ex.y = f2bf(dy * rn);
        ex.z = f2bf(dz * rn); ex.w = f2bf(aid);
        *(ushort4*)(f + 64) = ex;
    }
}

// ---------------------------------------------------------------------------
extern "C" void kernel_launch(void* const* d_in, const int* in_sizes, int n_in,
                              void* d_out, int out_size, void* d_ws, size_t ws_size,
                              hipStream_t stream)
{
    const float* x         = (const float*)d_in[0];
    const int*   col_index = (const int*)d_in[2];
    const int*   to_col    = (const int*)d_in[3];
    const float* att_bias  = (const float*)d_in[4];
    const float* dist      = (const float*)d_in[5];
    const float* pos       = (const float*)d_in[6];
    const float* col_pos   = (const float*)d_in[7];
    const float* Wq        = (const float*)d_in[8];
    const float* Wqv       = (const float*)d_in[9];
    const float* Wk        = (const float*)d_in[10];
    const float* Wv        = (const float*)d_in[11];
    const float* Wout      = (const float*)d_in[12];
    const float* bout      = (const float*)d_in[13];
    float* out = (float*)d_out;

    // Workspace layout (bytes); peak ~63.8 MB (round-1 proved ws >= ~69 MB).
    char* ws = (char*)d_ws;
    float* qk    = (float*)(ws + 0);              // [8192,1024] fp32  33,554,432
    u16*   v_bf  = (u16*)(ws + 33554432);         // [8192,512]  bf16   8,388,608
    u16*   xh    = (u16*)(ws + 41943040);         // [8192,512]  bf16   8,388,608
    u16*   xl    = (u16*)(ws + 50331648);         // [8192,512]  bf16   8,388,608
    u16*   Wh    = (u16*)(ws + 58720256);         // [1536,512]  bf16   1,572,864
    u16*   Wl    = (u16*)(ws + 60293120);         // [1536,512]  bf16   1,572,864
    float* qv_all= (float*)(ws + 61865984);       // [8192,24]   fp32     786,432
    u16*   Woth  = (u16*)(ws + 62652416);         // [512,544]   bf16     557,056
    u16*   Wotl  = (u16*)(ws + 63209472);         // [512,544]   bf16     557,056
    // feat overlays xh/xl (dead after projection GEMMs):
    u16*   feat  = xh;                            // [8192,544]  bf16   8,912,896

    const float scale = 0.125f;  // 1/sqrt(64), folded into Wq

    dim3 blk(256);

    // Splits
    hipLaunchKernelGGL(split2, dim3((N_NODES * D_FEAT / 4 + 255) / 256), blk, 0, stream,
                       x, xh, xl, N_NODES * D_FEAT / 4, 1.0f);
    hipLaunchKernelGGL(split2, dim3((D_FEAT * D_FEAT / 4 + 255) / 256), blk, 0, stream,
                       Wq, Wh, Wl, D_FEAT * D_FEAT / 4, scale);
    hipLaunchKernelGGL(split2, dim3((D_FEAT * D_FEAT / 4 + 255) / 256), blk, 0, stream,
                       Wk, Wh + 512 * 512, Wl + 512 * 512, D_FEAT * D_FEAT / 4, 1.0f);
    hipLaunchKernelGGL(split2, dim3((D_FEAT * D_FEAT / 4 + 255) / 256), blk, 0, stream,
                       Wv, Wh + 1024 * 512, Wl + 1024 * 512, D_FEAT * D_FEAT / 4, 1.0f);
    hipLaunchKernelGGL(split2, dim3((OUT_W * FEAT_W / 4 + 255) / 256), blk, 0, stream,
                       Wout, Woth, Wotl, OUT_W * FEAT_W / 4, 1.0f);

    // q|k projection: [8192,1024] fp32, 3-pass split
    hipLaunchKernelGGL((gemm_split<true, false>), dim3(8, 64), blk, 0, stream,
                       xh, xl, Wh, Wl, (const float*)nullptr, (void*)qk,
                       N_NODES, 1024, D_FEAT);
    // v projection: [8192,512] bf16 out, 3-pass split
    hipLaunchKernelGGL((gemm_split<true, true>), dim3(4, 64), blk, 0, stream,
                       xh, xl, Wh + 1024 * 512, Wl + 1024 * 512,
                       (const float*)nullptr, (void*)v_bf,
                       N_NODES, 512, D_FEAT);
    // qv projection (tiny, fp32)
    hipLaunchKernelGGL(gemm_abT, dim3(1, N_NODES / BM), blk, 0, stream,
                       x, Wqv, (const float*)nullptr, qv_all, N_NODES, 24, D_FEAT, 1.0f);

    // Edge stage
    hipLaunchKernelGGL(edge_kernel, dim3(N_NODES * H_HEADS / 16), blk, 0, stream,
                       qk, v_bf, qv_all, col_index, to_col, att_bias, dist,
                       pos, col_pos, feat);

    // Output GEMM: out = feat(bf16) @ (Woth+Wotl)^T + bout, 2-pass
    hipLaunchKernelGGL((gemm_split<false, false>), dim3(4, 64), blk, 0, stream,
                       feat, (const u16*)nullptr, Woth, Wotl, bout, (void*)out,
                       N_NODES, OUT_W, FEAT_W);
}

// Round 3
// 188.566 us; speedup vs baseline: 3.0292x; 1.6283x over previous
//
#include <hip/hip_runtime.h>
#include <math.h>

#define N_NODES 8192
#define D_FEAT  512
#define H_HEADS 8
#define DKH     64
#define DEG     16
#define E_EDGES (N_NODES * DEG)
#define FEAT_W  544      // 8 * (64 + 4)
#define OUT_W   512
#define QKV_W   1664     // 512 q | 512 k | 512 v | 24 qv | 104 pad  (13*128)

typedef unsigned short u16;
typedef __attribute__((ext_vector_type(8))) short short8;   // 8 bf16 for MFMA
typedef __attribute__((ext_vector_type(8))) unsigned short us8;
typedef __attribute__((ext_vector_type(4))) float f32x4;

// ---- bf16 helpers (RNE) ----------------------------------------------------
__device__ __forceinline__ u16 f2bf(float f) {
    union { float f; unsigned u; } c; c.f = f;
    unsigned u = c.u;
    unsigned r = u + 0x7FFFu + ((u >> 16) & 1u);
    return (u16)(r >> 16);
}
__device__ __forceinline__ float bf2f(u16 h) {
    union { unsigned u; float f; } c; c.u = ((unsigned)h) << 16;
    return c.f;
}

// ---- async global->LDS 16B -------------------------------------------------
__device__ __forceinline__ void async16(const void* g, void* l) {
#if __has_builtin(__builtin_amdgcn_global_load_lds)
    __builtin_amdgcn_global_load_lds(
        (const __attribute__((address_space(1))) void*)g,
        (__attribute__((address_space(3))) void*)l, 16, 0, 0);
#else
    *(float4*)l = *(const float4*)g;
#endif
}

// ---------------------------------------------------------------------------
// bf16 MFMA GEMM: C[M,N] = A[M,K] * B[N,K]^T (+bias). Optional split-B
// second pass (B = Bh + Bl) for ~fp32 weight precision.
// M%128==0, N%128==0, K%32==0. 256 threads = 4 waves; 128x128 tile.
// ---------------------------------------------------------------------------
template<bool HAS_BL, bool BF16_OUT>
__global__ __launch_bounds__(256) void gemm_mfma(
    const u16* __restrict__ Ah,
    const u16* __restrict__ Bh, const u16* __restrict__ Bl,
    const float* __restrict__ bias, void* __restrict__ Cout,
    int M, int N, int K)
{
    constexpr int NB = HAS_BL ? 2 : 1;
    __shared__ u16 smem[128 * 32 * (1 + NB)];
    u16* sAh = smem;
    u16* sBh = smem + 128 * 32;
    u16* sBl = smem + 128 * 32 * 2;   // used only if HAS_BL

    const int tid  = threadIdx.x;
    const int bm   = blockIdx.y * 128;
    const int bn   = blockIdx.x * 128;
    const int wave = tid >> 6;
    const int lane = tid & 63;
    const int wr   = (wave >> 1) * 64;
    const int wc   = (wave & 1) * 64;
    const int lrow = lane & 15;
    const int quad = lane >> 4;

    f32x4 acc[4][4];
    #pragma unroll
    for (int i = 0; i < 4; ++i)
        #pragma unroll
        for (int j = 0; j < 4; ++j) {
            f32x4 z = {0.f, 0.f, 0.f, 0.f};
            acc[i][j] = z;
        }

    for (int k0 = 0; k0 < K; k0 += 32) {
        #pragma unroll
        for (int i = 0; i < 2; ++i) {
            const int lin = i * 256 + tid;       // 16B-chunk index (512 total)
            const int row = lin >> 2;            // 0..127
            const int seg = (lin & 3) << 3;      // k offset 0/8/16/24
            const int loff = lin << 3;
            const size_t ga = (size_t)(bm + row) * K + k0 + seg;
            const size_t gb = (size_t)(bn + row) * K + k0 + seg;
            async16(Ah + ga, sAh + loff);
            async16(Bh + gb, sBh + loff);
            if (HAS_BL) async16(Bl + gb, sBl + loff);
        }
        __syncthreads();

        short8 a_h[4], b_h[4], b_l[4];
        #pragma unroll
        for (int t = 0; t < 4; ++t) {
            const int ar = (wr + t * 16 + lrow) * 32 + quad * 8;
            const int br = (wc + t * 16 + lrow) * 32 + quad * 8;
            a_h[t] = *(const short8*)&sAh[ar];
            b_h[t] = *(const short8*)&sBh[br];
            if (HAS_BL) b_l[t] = *(const short8*)&sBl[br];
        }

        #pragma unroll
        for (int mt = 0; mt < 4; ++mt)
            #pragma unroll
            for (int nt = 0; nt < 4; ++nt) {
                acc[mt][nt] = __builtin_amdgcn_mfma_f32_16x16x32_bf16(
                    a_h[mt], b_h[nt], acc[mt][nt], 0, 0, 0);
                if (HAS_BL)
                    acc[mt][nt] = __builtin_amdgcn_mfma_f32_16x16x32_bf16(
                        a_h[mt], b_l[nt], acc[mt][nt], 0, 0, 0);
            }
        __syncthreads();
    }

    // C/D layout: col = lane&15, row = quad*4 + r
    #pragma unroll
    for (int nt = 0; nt < 4; ++nt) {
        const int col = bn + wc + nt * 16 + lrow;
        const float bb = bias ? bias[col] : 0.f;
        #pragma unroll
        for (int mt = 0; mt < 4; ++mt) {
            #pragma unroll
            for (int r = 0; r < 4; ++r) {
                const int row = bm + wr + mt * 16 + quad * 4 + r;
                const float v = acc[mt][nt][r] + bb;
                if (BF16_OUT)
                    ((u16*)Cout)[(size_t)row * N + col] = f2bf(v);
                else
                    ((float*)Cout)[(size_t)row * N + col] = v;
            }
        }
    }
}

// ---------------------------------------------------------------------------
// fp32 -> bf16 convert (float4 -> ushort4), with scale.
// ---------------------------------------------------------------------------
__global__ __launch_bounds__(256) void cvt_bf16(
    const float* __restrict__ in, u16* __restrict__ out, int n4, float scale)
{
    const int i = blockIdx.x * 256 + threadIdx.x;
    if (i >= n4) return;
    float4 v = ((const float4*)in)[i];
    ushort4 h;
    h.x = f2bf(v.x * scale); h.y = f2bf(v.y * scale);
    h.z = f2bf(v.z * scale); h.w = f2bf(v.w * scale);
    ((ushort4*)out)[i] = h;
}

// fp32 -> (hi, lo) bf16 split for the 2-pass output GEMM weights.
__global__ __launch_bounds__(256) void split2(
    const float* __restrict__ in, u16* __restrict__ hi, u16* __restrict__ lo, int n4)
{
    const int i = blockIdx.x * 256 + threadIdx.x;
    if (i >= n4) return;
    const float4 v = ((const float4*)in)[i];
    ushort4 h, l;
    h.x = f2bf(v.x); l.x = f2bf(v.x - bf2f(h.x));
    h.y = f2bf(v.y); l.y = f2bf(v.y - bf2f(h.y));
    h.z = f2bf(v.z); l.z = f2bf(v.z - bf2f(h.z));
    h.w = f2bf(v.w); l.w = f2bf(v.w - bf2f(h.w));
    ((ushort4*)hi)[i] = h;
    ((ushort4*)lo)[i] = l;
}

// ---------------------------------------------------------------------------
// Build fused weight matrix B[1664, 512] bf16:
// rows 0-511 = Wq * 1/sqrt(64), 512-1023 = Wk, 1024-1535 = Wv,
// 1536-1559 = Wqv, 1560-1663 = 0.
// ---------------------------------------------------------------------------
__global__ __launch_bounds__(256) void build_B(
    const float* __restrict__ Wq, const float* __restrict__ Wk,
    const float* __restrict__ Wv, const float* __restrict__ Wqv,
    u16* __restrict__ B)
{
    const int idx = blockIdx.x * 256 + threadIdx.x;   // ushort4 index
    if (idx >= QKV_W * (D_FEAT / 4)) return;
    const int row = idx >> 7;           // /128
    const int c4  = idx & 127;
    float4 v = make_float4(0.f, 0.f, 0.f, 0.f);
    float scale = 1.f;
    if (row < 512) {
        v = *(const float4*)(Wq + (size_t)row * 512 + c4 * 4);
        scale = 0.125f;
    } else if (row < 1024) {
        v = *(const float4*)(Wk + (size_t)(row - 512) * 512 + c4 * 4);
    } else if (row < 1536) {
        v = *(const float4*)(Wv + (size_t)(row - 1024) * 512 + c4 * 4);
    } else if (row < 1560) {
        v = *(const float4*)(Wqv + (size_t)(row - 1536) * 512 + c4 * 4);
    }
    ushort4 h;
    h.x = f2bf(v.x * scale); h.y = f2bf(v.y * scale);
    h.z = f2bf(v.z * scale); h.w = f2bf(v.w * scale);
    ((ushort4*)B)[idx] = h;
}

// ---------------------------------------------------------------------------
// Edge stage: ONE WAVE PER NODE. lane = h*8 + sub; lane owns dims
// [sub*8, sub*8+8) of head h. A k/v row (1 KB bf16) is fetched by one
// fully-coalesced wave load. Edge metadata lives in lanes 0..15,
// broadcast via shuffles.
// ---------------------------------------------------------------------------
__global__ __launch_bounds__(256) void edge_kernel(
    const u16* __restrict__ qkv,        // [N, 1664] bf16
    const int* __restrict__ col_index, const int* __restrict__ to_col,
    const float* __restrict__ att_bias, const float* __restrict__ dist,
    const float* __restrict__ pos, const float* __restrict__ col_pos,
    u16* __restrict__ feat)             // [N, 544] bf16
{
    const int wave = threadIdx.x >> 6;
    const int lane = threadIdx.x & 63;
    const int n = blockIdx.x * 4 + wave;
    const int h = lane >> 3;
    const int sub = lane & 7;

    const size_t qbase = (size_t)n * QKV_W;

    // q fragment (8 dims), fp32
    float qf[8];
    {
        const us8 qu = *(const us8*)(qkv + qbase + h * DKH + sub * 8);
        #pragma unroll
        for (int i = 0; i < 8; ++i) qf[i] = bf2f(qu[i]);
    }
    // qv (3 per head) via wave shuffle from the 24 bf16 at col 1536
    float qv0, qv1, qv2;
    {
        const float qvl = bf2f(qkv[qbase + 1536 + (lane < 24 ? lane : 0)]);
        qv0 = __shfl(qvl, h * 3 + 0);
        qv1 = __shfl(qvl, h * 3 + 1);
        qv2 = __shfl(qvl, h * 3 + 2);
    }
    const float px = pos[3 * n + 0], py = pos[3 * n + 1], pz = pos[3 * n + 2];

    // per-edge metadata in lanes 0..15 (lanes 16+ hold duplicates)
    const int j16 = lane & 15;
    const int e0  = n * DEG + j16;
    const int c_l  = col_index[e0];
    const int cc_l = to_col[c_l];
    const float d_l = dist[e0];
    const float invd_l = (d_l == 0.f) ? 0.f : (1.f / d_l);
    const float rx_l = col_pos[3 * c_l + 0] - px;
    const float ry_l = col_pos[3 * c_l + 1] - py;
    const float rz_l = col_pos[3 * c_l + 2] - pz;

    // bias: lane (h,sub) preloads edges sub*2, sub*2+1 of head h
    const float b0 = att_bias[(size_t)h * E_EDGES + n * DEG + sub * 2 + 0];
    const float b1 = att_bias[(size_t)h * E_EDGES + n * DEG + sub * 2 + 1];

    // ---- pass 1: logits -----------------------------------------------------
    float logit[DEG];
    #pragma unroll
    for (int j = 0; j < DEG; ++j) {
        const int cc = __shfl(cc_l, j);
        const us8 ku = *(const us8*)(qkv + (size_t)cc * QKV_W + 512 + h * DKH + sub * 8);
        float dot = 0.f;
        #pragma unroll
        for (int i = 0; i < 8; ++i) dot += qf[i] * bf2f(ku[i]);
        dot += __shfl_xor(dot, 1, 8);
        dot += __shfl_xor(dot, 2, 8);
        dot += __shfl_xor(dot, 4, 8);
        const float invd = __shfl(invd_l, j);
        const float ang = qv0 * __shfl(rx_l, j) + qv1 * __shfl(ry_l, j)
                        + qv2 * __shfl(rz_l, j);
        const float bj = __shfl((j & 1) ? b1 : b0, j >> 1, 8);
        logit[j] = dot + bj + ang * invd;
    }

    // ---- softmax over 16 edges (replicated across the 8 dim-lanes) ---------
    float m = logit[0];
    #pragma unroll
    for (int j = 1; j < DEG; ++j) m = fmaxf(m, logit[j]);
    float s = 0.f;
    #pragma unroll
    for (int j = 0; j < DEG; ++j) { logit[j] = __expf(logit[j] - m); s += logit[j]; }
    const float inv_s = 1.f / s;

    // ---- pass 2: weighted accumulation -------------------------------------
    float y[8] = {0.f, 0.f, 0.f, 0.f, 0.f, 0.f, 0.f, 0.f};
    float dx = 0.f, dy = 0.f, dz = 0.f, aid = 0.f;
    #pragma unroll
    for (int j = 0; j < DEG; ++j) {
        const float a = logit[j] * inv_s;
        const int cc = __shfl(cc_l, j);
        const us8 vu = *(const us8*)(qkv + (size_t)cc * QKV_W + 1024 + h * DKH + sub * 8);
        #pragma unroll
        for (int i = 0; i < 8; ++i) y[i] += a * bf2f(vu[i]);
        const float na = a * __shfl(invd_l, j);
        dx += na * __shfl(rx_l, j);      // dst_vec - src_vec == sum na*rel
        dy += na * __shfl(ry_l, j);
        dz += na * __shfl(rz_l, j);
        aid += na;
    }

    // ---- write feat ---------------------------------------------------------
    u16* f = feat + (size_t)n * FEAT_W + h * (DKH + 4);
    ushort4 o0, o1;
    o0.x = f2bf(y[0]); o0.y = f2bf(y[1]); o0.z = f2bf(y[2]); o0.w = f2bf(y[3]);
    o1.x = f2bf(y[4]); o1.y = f2bf(y[5]); o1.z = f2bf(y[6]); o1.w = f2bf(y[7]);
    *(ushort4*)(f + sub * 8 + 0) = o0;
    *(ushort4*)(f + sub * 8 + 4) = o1;
    if (sub == 0) {
        const float nrm = sqrtf(dx * dx + dy * dy + dz * dz);
        const float rn = 1.f / fmaxf(nrm, 1e-12f);
        ushort4 ex;
        ex.x = f2bf(dx * rn); ex.y = f2bf(dy * rn);
        ex.z = f2bf(dz * rn); ex.w = f2bf(aid);
        *(ushort4*)(f + DKH) = ex;
    }
}

// ---------------------------------------------------------------------------
extern "C" void kernel_launch(void* const* d_in, const int* in_sizes, int n_in,
                              void* d_out, int out_size, void* d_ws, size_t ws_size,
                              hipStream_t stream)
{
    const float* x         = (const float*)d_in[0];
    const int*   col_index = (const int*)d_in[2];
    const int*   to_col    = (const int*)d_in[3];
    const float* att_bias  = (const float*)d_in[4];
    const float* dist      = (const float*)d_in[5];
    const float* pos       = (const float*)d_in[6];
    const float* col_pos   = (const float*)d_in[7];
    const float* Wq        = (const float*)d_in[8];
    const float* Wqv       = (const float*)d_in[9];
    const float* Wk        = (const float*)d_in[10];
    const float* Wv        = (const float*)d_in[11];
    const float* Wout      = (const float*)d_in[12];
    const float* bout      = (const float*)d_in[13];
    float* out = (float*)d_out;

    // Workspace layout (bytes), total ~47.4 MB
    char* ws = (char*)d_ws;
    u16* qkv   = (u16*)(ws + 0);           // [8192,1664] bf16  27,262,976
    u16* xh    = (u16*)(ws + 27262976);    // [8192,512]  bf16   8,388,608
    u16* Bfuse = (u16*)(ws + 35651584);    // [1664,512]  bf16   1,703,936
    u16* Woth  = (u16*)(ws + 37355520);    // [512,544]   bf16     557,056
    u16* Wotl  = (u16*)(ws + 37912576);    // [512,544]   bf16     557,056
    u16* feat  = (u16*)(ws + 38469632);    // [8192,544]  bf16   8,912,896

    dim3 blk(256);

    // Converts
    hipLaunchKernelGGL(cvt_bf16, dim3(N_NODES * D_FEAT / 4 / 256), blk, 0, stream,
                       x, xh, N_NODES * D_FEAT / 4, 1.0f);
    hipLaunchKernelGGL(build_B, dim3((QKV_W * (D_FEAT / 4) + 255) / 256), blk, 0, stream,
                       Wq, Wk, Wv, Wqv, Bfuse);
    hipLaunchKernelGGL(split2, dim3((OUT_W * FEAT_W / 4 + 255) / 256), blk, 0, stream,
                       Wout, Woth, Wotl, OUT_W * FEAT_W / 4);

    // Fused q|k|v|qv projection: [8192,1664] bf16, 1-pass
    hipLaunchKernelGGL((gemm_mfma<false, true>), dim3(QKV_W / 128, N_NODES / 128),
                       blk, 0, stream,
                       xh, Bfuse, (const u16*)nullptr, (const float*)nullptr,
                       (void*)qkv, N_NODES, QKV_W, D_FEAT);

    // Edge stage: wave per node
    hipLaunchKernelGGL(edge_kernel, dim3(N_NODES / 4), blk, 0, stream,
                       qkv, col_index, to_col, att_bias, dist, pos, col_pos, feat);

    // Output GEMM: out = feat(bf16) @ (Woth+Wotl)^T + bout, 2-pass
    hipLaunchKernelGGL((gemm_mfma<true, false>), dim3(OUT_W / 128, N_NODES / 128),
                       blk, 0, stream,
                       feat, Woth, Wotl, bout, (void*)out,
                       N_NODES, OUT_W, FEAT_W);
}